// Round 5
// baseline (190.655 us; speedup 1.0000x reference)
//
#include <hip/hip_runtime.h>

// PatchEncoder fused kernel, round 8.
// out[b, (h/16)*32 + w/16, (h%16)*48 + (w%16)*3 + c]
//   = conv3x3_SAME(X)[b,h,w,c] + bias[c]
//     + pos_emb[(h/4)*128 + (w/4), (h%4)*12 + (w%4)*3 + c]
//
// History: R4 69us, R5 86us (no-LDS: scattered loads lose), R6 63.7us
// (2 rows/thr + LDS out-stage; occ 35.7% capped by 35.8KB LDS),
// R7 FAILED absmax=6.06 — prime suspect: 12B global_load_lds lane->LDS
// mapping is unverified HW semantics (16B variant is measured: base+16*i).
//
// R8 = R7's goals via verified 16B DMA only:
//  - Input tile [34 rows][stride 200 floats] filled FLAT by 27 full-wave
//    16B DMAs. Per-lane GLOBAL address is pre-swizzled (m173 pattern):
//    for LDS float f=256d+4*lane: row=f/200, o=f%200, src = Xb +
//    (h0-1+row)*1536 + (3*w0-4) + o. Halos (o<4, o>=196) come from the
//    same loads (adjacent-row pixels, zero-fixed at edges).
//  - LDS 27.65KB -> 5 blocks/CU (62.5% cap vs R6 50%/measured 35.7%).
//  - Fetch 27.6KB/block vs R6 34.8KB; no separate halo path.
//  - Per-lane pointer clamps only on edge blocks (block-uniform).
//  - Out-stage [row16][patch8][48f] stride 388 (odd granule -> writer
//    bank residues uniform over 8), drain via exact const-div remap.
// Input LDS map: row r (global h0-1+r), float o <-> global 3*w0-4+o.
//   Compute reads s[1..18] => o in [12g+1, 12g+18]; o=0/199 never read.

#define BATCH 32
#define IMH 512
#define IMW 512
#define RSF 200            // input row stride, floats
#define NROW 34
#define NDMA 27            // ceil(34*200/256.)
#define OSTRIDE 388        // out-stage row stride, floats (granule 97, odd)
#define TILEW 64
#define TILEH 32

__device__ __forceinline__ void dma16(const float* g, float* l) {
    __builtin_amdgcn_global_load_lds(
        (const __attribute__((address_space(1))) void*)g,
        (__attribute__((address_space(3))) void*)l,
        16, 0, 0);
}

__global__ __launch_bounds__(256, 5) void patch_enc_kernel(
    const float* __restrict__ X,     // [B,H,W,3] NHWC
    const float* __restrict__ Kw,    // [3,3,3,3] HWIO
    const float* __restrict__ bias,  // [3]
    const float* __restrict__ pos,   // [16384,48]
    float* __restrict__ out)         // [B,1024,768]
{
    __shared__ float lds[NDMA * 256];   // 6912 floats = 27.65 KB

    const int tid = threadIdx.x;
    const int w0  = blockIdx.x * TILEW;
    const int h0  = blockIdx.y * TILEH;
    const int b   = blockIdx.z;

    const bool lEdge = (w0 == 0);
    const bool rEdge = (w0 == IMW - TILEW);
    const bool tEdge = (h0 == 0);
    const bool bEdge = (h0 == IMH - TILEH);
    const bool edge  = lEdge | rEdge | tEdge | bEdge;

    const float* Xb = X + (size_t)b * (IMH * IMW * 3);

    // ---- async-stage: 27 flat 16B DMAs fill [34][200] incl. halos ----
    {
        const int lane = tid & 63;
        const int wv   = tid >> 6;
        const float* xlo = X;
        const float* xhi = X + (size_t)BATCH * IMH * IMW * 3 - 4;   // last 16B start
        // tile origin: row 0, o 0  <->  global float (h0-1)*1536 + 3*w0 - 4
        const float* Xt = Xb + (long)(h0 - 1) * (IMW * 3) + (3 * w0 - 4);
        for (int d = wv; d < NDMA; d += 4) {
            const int f   = 256 * d + 4 * lane;     // LDS float index
            const int row = f / 200;                // const-divisor magic-mul
            const int o   = f - 200 * row;
            const float* gp = Xt + row * (IMW * 3) + o;
            if (edge) {                             // block-uniform; per-lane clamp
                gp = (gp < xlo) ? xlo : gp;
                gp = (gp > xhi) ? xhi : gp;
            }
            dma16(gp, &lds[256 * d]);
        }
    }

    // weights while DMA is in flight: uniform -> s_load -> SGPR operands
    float wk[81];
#pragma unroll
    for (int i = 0; i < 81; ++i) wk[i] = Kw[i];
    const float bs0 = bias[0], bs1 = bias[1], bs2 = bias[2];

    __syncthreads();   // drains vmcnt: whole tile landed

    // ---- zero-pad fixups, edge blocks only (block-uniform branch) ----
    if (edge) {
        if (tEdge) for (int j = tid; j < RSF; j += 256) lds[j] = 0.0f;                    // h=-1
        if (bEdge) for (int j = tid; j < RSF; j += 256) lds[(NROW - 1) * RSF + j] = 0.0f; // h=512
        if (lEdge && tid < NROW) {
            float* p = &lds[tid * RSF];
            p[1] = 0.0f; p[2] = 0.0f; p[3] = 0.0f;            // col w=-1
        }
        if (rEdge && tid < NROW) {
            float* p = &lds[tid * RSF + 196];
            p[0] = 0.0f; p[1] = 0.0f; p[2] = 0.0f;            // col w=512
        }
        __syncthreads();
    }

    // ---- compute: thread -> rows {h0+2*r2, +1}, col group g (4 px) ----
    const int g  = tid & 15;
    const int r2 = tid >> 4;

    float acc0[12], acc1[12];
#pragma unroll
    for (int i = 0; i < 12; ++i) { acc0[i] = 0.0f; acc1[i] = 0.0f; }

    // LDS row (2*r2+q): feeds out-row0 with weight-row q (q<=2),
    // out-row1 with weight-row q-1 (q>=1). 4 rows read for 2 computed.
#pragma unroll
    for (int q = 0; q < 4; ++q) {
        const float* bp = &lds[(2 * r2 + q) * RSF + 12 * g];
        float s[20];
#pragma unroll
        for (int j = 0; j < 5; ++j)
            *(float4*)&s[4 * j] = *(const float4*)(bp + 4 * j);   // ds_read_b128
#pragma unroll
        for (int dc = 0; dc < 3; ++dc)
#pragma unroll
        for (int ci = 0; ci < 3; ++ci) {
#pragma unroll
            for (int i = 0; i < 4; ++i) {
                const float x = s[3 * (i + dc) + ci + 1];
                if (q <= 2) {
                    const float* wp = &wk[((q * 3 + dc) * 3 + ci) * 3];
                    acc0[i * 3 + 0] = fmaf(x, wp[0], acc0[i * 3 + 0]);
                    acc0[i * 3 + 1] = fmaf(x, wp[1], acc0[i * 3 + 1]);
                    acc0[i * 3 + 2] = fmaf(x, wp[2], acc0[i * 3 + 2]);
                }
                if (q >= 1) {
                    const float* wp = &wk[(((q - 1) * 3 + dc) * 3 + ci) * 3];
                    acc1[i * 3 + 0] = fmaf(x, wp[0], acc1[i * 3 + 0]);
                    acc1[i * 3 + 1] = fmaf(x, wp[1], acc1[i * 3 + 1]);
                    acc1[i * 3 + 2] = fmaf(x, wp[2], acc1[i * 3 + 2]);
                }
            }
        }
    }

    // ---- bias + pos_emb (adjacent rows share n: one 96B load) ----
    const int hg0 = h0 + 2 * r2;
    const int wg0 = w0 + 4 * g;
    const int n   = (hg0 >> 2) * 128 + (wg0 >> 2);
    const float* pp = pos + (size_t)n * 48 + (hg0 & 3) * 12;   // 16B aligned
    float pr[24];
#pragma unroll
    for (int j = 0; j < 6; ++j)
        *(float4*)&pr[4 * j] = *(const float4*)(pp + 4 * j);

    float v0[12], v1[12];
#pragma unroll
    for (int k = 0; k < 12; ++k) {
        const float bsk = (k % 3 == 0) ? bs0 : (k % 3 == 1) ? bs1 : bs2;
        v0[k] = acc0[k] + bsk + pr[k];
        v1[k] = acc1[k] + bsk + pr[12 + k];
    }

    __syncthreads();   // all input-LDS reads done; reuse buffer for out-stage

    // ---- out-stage: [row16][patch8][48f], stride 388 (odd granule) ----
    {
        const int rw = (2 * r2) & 15;                         // row in patch (even)
        const int p  = ((2 * r2) >> 4) * 4 + (g >> 2);        // local patch 0..7
        const int o0 = rw * OSTRIDE + p * 48 + (g & 3) * 12;
        *(float4*)&lds[o0 + 0] = make_float4(v0[0], v0[1], v0[2],  v0[3]);
        *(float4*)&lds[o0 + 4] = make_float4(v0[4], v0[5], v0[6],  v0[7]);
        *(float4*)&lds[o0 + 8] = make_float4(v0[8], v0[9], v0[10], v0[11]);
        const int o1 = o0 + OSTRIDE;                          // row+1, same patch
        *(float4*)&lds[o1 + 0] = make_float4(v1[0], v1[1], v1[2],  v1[3]);
        *(float4*)&lds[o1 + 4] = make_float4(v1[4], v1[5], v1[6],  v1[7]);
        *(float4*)&lds[o1 + 8] = make_float4(v1[8], v1[9], v1[10], v1[11]);
    }
    __syncthreads();

    // ---- coalesced store: two contiguous 12KB regions (np0+0..3, +32..35) ----
    {
        float* ob = out + (size_t)b * 786432
                  + (size_t)((h0 >> 4) * 32 + (w0 >> 4)) * 768;
#pragma unroll
        for (int c = 0; c < 6; ++c) {
            const int fl  = 4 * tid + 1024 * c;     // logical float offset
            const int p   = fl / 768;               // exact const-div
            const int rem = fl - 768 * p;
            const int rw  = rem / 48;
            const int cg  = rem - 48 * rw;
            const float4 val = *(const float4*)&lds[rw * OSTRIDE + p * 48 + cg];
            const int go = (p < 4) ? fl : fl + 21504;   // region 1 at np0+32
            *(float4*)(ob + go) = val;
        }
    }
}

extern "C" void kernel_launch(void* const* d_in, const int* in_sizes, int n_in,
                              void* d_out, int out_size, void* d_ws, size_t ws_size,
                              hipStream_t stream) {
    const float* X    = (const float*)d_in[0];
    const float* Kw   = (const float*)d_in[1];
    const float* bias = (const float*)d_in[2];
    const float* pos  = (const float*)d_in[3];
    float* out = (float*)d_out;

    dim3 grid(IMW / TILEW, IMH / TILEH, BATCH);   // 8 x 16 x 32 = 4096 blocks
    patch_enc_kernel<<<grid, 256, 0, stream>>>(X, Kw, bias, pos, out);
}